// Round 6
// baseline (566.790 us; speedup 1.0000x reference)
//
#include <hip/hip_runtime.h>

// ---------------- common types/helpers ----------------
typedef float fx4 __attribute__((ext_vector_type(4)));
typedef short s16x4 __attribute__((ext_vector_type(4)));
typedef short s16x8 __attribute__((ext_vector_type(8)));
typedef __bf16 bf16x8 __attribute__((ext_vector_type(8)));

__device__ __forceinline__ short f2bf(float f) {
  unsigned u = __builtin_bit_cast(unsigned, f);
  u += 0x7fffu + ((u >> 16) & 1u);   // RNE
  return (short)(u >> 16);
}

__device__ __forceinline__ bf16x8 ld8(const short* p) {
  s16x8 v = *(const s16x8*)p;
  return __builtin_bit_cast(bf16x8, v);
}

// async global->LDS, 16B per lane; LDS dest is wave-uniform base + lane*16
__device__ __forceinline__ void gld16(const void* g, void* l) {
  __builtin_amdgcn_global_load_lds(
      (const __attribute__((address_space(1))) unsigned*)g,
      (__attribute__((address_space(3))) unsigned*)l, 16, 0, 0);
}

// ---------------- f32 -> bf16 convert (x pre-conversion) ----------------
__global__ __launch_bounds__(256) void cvt_k(const float* __restrict__ in,
                                             short* __restrict__ out) {
  int i = (blockIdx.x * 256 + threadIdx.x) * 8;
  fx4 a = *(const fx4*)(in + i);
  fx4 b = *(const fx4*)(in + i + 4);
  s16x8 w;
  w[0] = f2bf(a[0]); w[1] = f2bf(a[1]); w[2] = f2bf(a[2]); w[3] = f2bf(a[3]);
  w[4] = f2bf(b[0]); w[5] = f2bf(b[1]); w[6] = f2bf(b[2]); w[7] = f2bf(b[3]);
  *(s16x8*)(out + i) = w;
}

// ---------------- transpose+convert: out[n][k] = bf16(in[k][n]) ----------------
// in: f32 [K,N] row-major; out: bf16 [N,K]; 64x64 tiles, 256 threads
__global__ __launch_bounds__(256) void tr_k(const float* __restrict__ in,
    short* __restrict__ out, int K, int N) {
  __shared__ short T[64][72];
  const int ktiles = K >> 6;
  const int tk0 = (blockIdx.x % ktiles) << 6;
  const int tn0 = (blockIdx.x / ktiles) << 6;
  const int tid = threadIdx.x;
  #pragma unroll
  for (int i = 0; i < 4; ++i) {
    int idx = i * 256 + tid;
    int k = idx >> 4, n4 = (idx & 15) << 2;
    fx4 v = *(const fx4*)(in + (size_t)(tk0 + k) * N + tn0 + n4);
    #pragma unroll
    for (int j = 0; j < 4; ++j) T[n4 + j][k] = f2bf(v[j]);
  }
  __syncthreads();
  #pragma unroll
  for (int i = 0; i < 2; ++i) {
    int idx = i * 256 + tid;
    int n = idx >> 3, k8 = (idx & 7) << 3;
    *(s16x8*)(out + (size_t)(tn0 + n) * K + tk0 + k8) = *(const s16x8*)&T[n][k8];
  }
}

// ---------------- V transpose: vbt[b][kvh][d][t] = vbp[t(b)][kvh][d] -------
// vbp: bf16 [2048][8][128]; vbt: bf16 [2][8][128][1024]; 64x64 tiles
__global__ __launch_bounds__(256) void vtr_k(const short* __restrict__ vbp,
                                             short* __restrict__ vbt) {
  __shared__ short T[64][72];   // T[d][t]
  const int tile = blockIdx.x & 31;
  const int tt = tile & 15, dt = tile >> 4;
  const int bk = blockIdx.x >> 5;
  const int b = bk >> 3, kvh = bk & 7;
  const int t0 = tt << 6, d0 = dt << 6;
  const int tid = threadIdx.x;
  #pragma unroll
  for (int i = 0; i < 2; ++i) {
    int idx = i * 256 + tid;
    int r = idx >> 3, c8 = (idx & 7) << 3;   // r = t-row, c8 = d-col
    s16x8 v = *(const s16x8*)(vbp + (size_t)(b * 1024 + t0 + r) * 1024 + kvh * 128 + d0 + c8);
    #pragma unroll
    for (int j = 0; j < 8; ++j) T[c8 + j][r] = v[j];
  }
  __syncthreads();
  #pragma unroll
  for (int i = 0; i < 2; ++i) {
    int idx = i * 256 + tid;
    int r = idx >> 3, c8 = (idx & 7) << 3;   // r = d-row, c8 = t-col
    *(s16x8*)(vbt + ((size_t)(b * 8 + kvh) * 128 + d0 + r) * 1024 + t0 + c8) =
        *(const s16x8*)&T[r][c8];
  }
}

// ---------------- GEMM: C[M,N] = A[M,K] @ Bt[N,K]^T  (all bf16 in, f32 out) ----
// 128x128 tile, BK=64, 4 waves (2x2), 4x4 16x16x32 frags/wave, 32 MFMA/step.
// T3 2-phase double-buffered pipeline; one __syncthreads per K-step.
__global__ __launch_bounds__(256) void gemm_k(const short* __restrict__ A,
    const short* __restrict__ Bt, float* __restrict__ Cp, int N, int K) {
  __shared__ short As[2][128 * 64];
  __shared__ short Bs[2][128 * 64];
  const int tiles_n = N >> 7;
  const int tm = blockIdx.x / tiles_n, tn = blockIdx.x % tiles_n;
  const int tid = threadIdx.x;
  const int lane = tid & 63, wv = tid >> 6;
  const int wr = (wv >> 1) << 6, wc = (wv & 1) << 6;
  const int r0 = tm << 7, c0 = tn << 7;
  const int lrow = lane & 15, lg = lane >> 4;
  const int srow = tid >> 3, sch = tid & 7;   // staging: 8 chunks per row
  fx4 acc[4][4] = {};

  auto stage = [&](int buf, int k0) {
    #pragma unroll
    for (int i = 0; i < 4; ++i) {
      int row = (i << 5) + srow;
      int gk = ((sch ^ (row & 7)) << 3);
      gld16(A + (size_t)(r0 + row) * K + k0 + gk, &As[buf][(i * 256 + wv * 64) * 8]);
    }
    #pragma unroll
    for (int i = 0; i < 4; ++i) {
      int row = (i << 5) + srow;
      int gk = ((sch ^ (row & 7)) << 3);
      gld16(Bt + (size_t)(c0 + row) * K + k0 + gk, &Bs[buf][(i * 256 + wv * 64) * 8]);
    }
  };

  const int nt = K >> 6;
  stage(0, 0);
  __syncthreads();          // drain prologue loads
  int cur = 0;
  for (int t = 0; t < nt; ++t) {
    if (t + 1 < nt) stage(cur ^ 1, (t + 1) << 6);   // loads fly during compute
    bf16x8 af[4][2], bfr[4][2];
    #pragma unroll
    for (int m = 0; m < 4; ++m) {
      int row = wr + m * 16 + lrow;
      #pragma unroll
      for (int h = 0; h < 2; ++h)
        af[m][h] = ld8(&As[cur][row * 64 + ((((h << 2) + lg) ^ (row & 7)) << 3)]);
    }
    #pragma unroll
    for (int n = 0; n < 4; ++n) {
      int row = wc + n * 16 + lrow;
      #pragma unroll
      for (int h = 0; h < 2; ++h)
        bfr[n][h] = ld8(&Bs[cur][row * 64 + ((((h << 2) + lg) ^ (row & 7)) << 3)]);
    }
    __builtin_amdgcn_s_setprio(1);
    #pragma unroll
    for (int m = 0; m < 4; ++m)
      #pragma unroll
      for (int n = 0; n < 4; ++n) {
        acc[m][n] = __builtin_amdgcn_mfma_f32_16x16x32_bf16(af[m][0], bfr[n][0], acc[m][n], 0, 0, 0);
        acc[m][n] = __builtin_amdgcn_mfma_f32_16x16x32_bf16(af[m][1], bfr[n][1], acc[m][n], 0, 0, 0);
      }
    __builtin_amdgcn_s_setprio(0);
    __syncthreads();        // drains vmcnt(0)+lgkmcnt(0): next tile resident, swap safe
    cur ^= 1;
  }
  // ---- epilogue: C layout col=lane&15, row=(lane>>4)*4+j ----
  const int g4 = lg << 2;
  #pragma unroll
  for (int m = 0; m < 4; ++m)
    #pragma unroll
    for (int n = 0; n < 4; ++n)
      #pragma unroll
      for (int j = 0; j < 4; ++j) {
        int row = r0 + wr + m * 16 + g4 + j;
        int col = c0 + wc + n * 16 + lrow;
        Cp[(size_t)row * N + col] = acc[m][n][j];
      }
}

// ---------------- RMSNorm + RoPE + KV scatter ----------------
// one wave per (token, head) row; lane l holds d=l and d=l+64 (rotate-half pairs)
// xqkv: f32 [2048][6144] — q at +0, k at +4096, v at +5120 (per token row)
__global__ __launch_bounds__(256) void nr_k(const float* __restrict__ xqkv,
    const float* __restrict__ qnw, const float* __restrict__ knw,
    const float* __restrict__ cosb, const float* __restrict__ sinb,
    const int* __restrict__ idx,
    short* __restrict__ qb, short* __restrict__ kbp, short* __restrict__ vbp,
    float* __restrict__ bufo) {
  int rid = blockIdx.x * 4 + (threadIdx.x >> 6);
  int l = threadIdx.x & 63;
  int type, t, h;
  if (rid < 65536)      { type = 0; t = rid >> 5; h = rid & 31; }
  else if (rid < 81920) { type = 1; int r = rid - 65536; t = r >> 3; h = r & 7; }
  else                  { type = 2; int r = rid - 81920; t = r >> 3; h = r & 7; }
  int s = t & 1023;
  const float* src = xqkv + (size_t)t * 6144 +
                     ((type == 0) ? h * 128 : (type == 1) ? 4096 + h * 128
                                                          : 5120 + h * 128);
  float e0 = src[l], e1 = src[l + 64];
  float out0, out1;
  if (type < 2) {
    float ss = e0 * e0 + e1 * e1;
    #pragma unroll
    for (int off = 1; off < 64; off <<= 1) ss += __shfl_xor(ss, off);
    float r = rsqrtf(ss * (1.0f / 128.0f) + 1e-6f);
    const float* nw = (type == 0) ? qnw : knw;
    float n0 = e0 * r * nw[l], n1 = e1 * r * nw[l + 64];
    float c0 = cosb[s * 128 + l], c1 = cosb[s * 128 + 64 + l];
    float s0 = sinb[s * 128 + l], s1 = sinb[s * 128 + 64 + l];
    out0 = n0 * c0 - n1 * s0;
    out1 = n1 * c1 + n0 * s1;
  } else { out0 = e0; out1 = e1; }
  if (type == 0) {
    short* d = qb + (size_t)t * 4096 + h * 128;
    d[l] = f2bf(out0); d[l + 64] = f2bf(out1);
  } else {
    int br = idx[t];
    float* bd = bufo + (size_t)br * 2048 + (type == 1 ? 0 : 1024) + h * 128;
    bd[l] = out0; bd[l + 64] = out1;
    short* d = (type == 1) ? kbp + (size_t)t * 1024 + h * 128
                           : vbp + (size_t)t * 1024 + h * 128;
    d[l] = f2bf(out0); d[l + 64] = f2bf(out1);
  }
}

// ---------------- causal GQA flash attention (no K/V staging) ----------------
// block = (b, h, 64-q-row tile), 4 waves of 16 q rows each, KV tiles of 64.
// K/V are L2-resident (256 KB per (b,kvh), reused by 64 blocks): fragments are
// read DIRECTLY from global (K row-major, V pre-transposed in vbt), no LDS
// staging, no barriers in the kt loop. Ps is per-wave (compiler-ordered LDS).
#define PLD 72

__global__ __launch_bounds__(256) void attn_k(const short* __restrict__ qb,
    const short* __restrict__ kbp, const short* __restrict__ vbt,
    short* __restrict__ ob) {
  __shared__ short Ps[4][16 * PLD];
  const int bid = blockIdx.x;
  const int qt = bid & 15, h = (bid >> 4) & 31, b = bid >> 9;
  const int kvh = h >> 2;
  const int tid = threadIdx.x, lane = tid & 63, w = tid >> 6;
  const int lrow = lane & 15, lg = lane >> 4, lk = lg << 3;
  const int q0 = qt << 6;
  const float SC2 = 0.088388347648318447f * 1.4426950408889634f; // scale*log2(e)

  bf16x8 qf[4];
  {
    const short* qp = qb + ((size_t)(b * 1024 + q0 + w * 16 + lrow) * 32 + h) * 128 + lk;
    #pragma unroll
    for (int kb4 = 0; kb4 < 4; ++kb4) qf[kb4] = ld8(qp + kb4 * 32);
  }
  // K rows: kbp[(b*1024 + t)*1024 + kvh*128 + d];  V^T rows: vbt[((b*8+kvh)*128+d)*1024 + t]
  const short* kb_base = kbp + (size_t)(b * 1024) * 1024 + kvh * 128;
  const short* vt_base = vbt + (size_t)(b * 8 + kvh) * 128 * 1024;

  float m[4], lsum[4];
  fx4 acc[8] = {};
  #pragma unroll
  for (int j = 0; j < 4; ++j) { m[j] = -3.0e38f; lsum[j] = 0.f; }

  for (int kt = 0; kt <= qt; ++kt) {
    const int kv0 = kt << 6;
    // S = Q K^T (16x64 per wave), K-fragments direct from global (L2-hit)
    fx4 sf[4];
    #pragma unroll
    for (int np = 0; np < 2; ++np) {
      bf16x8 kf[2][4];
      #pragma unroll
      for (int u = 0; u < 2; ++u)
        #pragma unroll
        for (int kb4 = 0; kb4 < 4; ++kb4)
          kf[u][kb4] = ld8(kb_base + (size_t)(kv0 + (np * 2 + u) * 16 + lrow) * 1024
                           + kb4 * 32 + lk);
      #pragma unroll
      for (int u = 0; u < 2; ++u) {
        fx4 z = {0.f, 0.f, 0.f, 0.f};
        fx4 s = z;
        #pragma unroll
        for (int kb4 = 0; kb4 < 4; ++kb4)
          s = __builtin_amdgcn_mfma_f32_16x16x32_bf16(qf[kb4], kf[u][kb4], s, 0, 0, 0);
        sf[np * 2 + u] = s;
      }
    }
    // causal mask on the diagonal tile
    if (kt == qt) {
      #pragma unroll
      for (int nc = 0; nc < 4; ++nc)
        #pragma unroll
        for (int j = 0; j < 4; ++j) {
          int qr = q0 + w * 16 + (lg << 2) + j;
          int kc = kv0 + nc * 16 + lrow;
          if (kc > qr) sf[nc][j] = -3.0e38f;
        }
    }
    // online softmax (rows live in lanes sharing lg; reduce over low 4 lane bits)
    float pm[4];
    #pragma unroll
    for (int j = 0; j < 4; ++j) pm[j] = -3.0e38f;
    #pragma unroll
    for (int nc = 0; nc < 4; ++nc)
      #pragma unroll
      for (int j = 0; j < 4; ++j) pm[j] = fmaxf(pm[j], sf[nc][j]);
    #pragma unroll
    for (int j = 0; j < 4; ++j) {
      pm[j] = fmaxf(pm[j], __shfl_xor(pm[j], 1));
      pm[j] = fmaxf(pm[j], __shfl_xor(pm[j], 2));
      pm[j] = fmaxf(pm[j], __shfl_xor(pm[j], 4));
      pm[j] = fmaxf(pm[j], __shfl_xor(pm[j], 8));
    }
    float alpha[4], rs[4];
    #pragma unroll
    for (int j = 0; j < 4; ++j) {
      float mn = fmaxf(m[j], pm[j]);
      alpha[j] = exp2f((m[j] - mn) * SC2);
      m[j] = mn;
      rs[j] = 0.f;
    }
    #pragma unroll
    for (int nc = 0; nc < 4; ++nc)
      #pragma unroll
      for (int j = 0; j < 4; ++j) {
        float p = exp2f((sf[nc][j] - m[j]) * SC2);
        rs[j] += p;
        Ps[w][((lg << 2) + j) * PLD + nc * 16 + lrow] = f2bf(p);
      }
    #pragma unroll
    for (int j = 0; j < 4; ++j) {
      rs[j] += __shfl_xor(rs[j], 1);
      rs[j] += __shfl_xor(rs[j], 2);
      rs[j] += __shfl_xor(rs[j], 4);
      rs[j] += __shfl_xor(rs[j], 8);
      lsum[j] = lsum[j] * alpha[j] + rs[j];
    }
    #pragma unroll
    for (int dg = 0; dg < 8; ++dg)
      #pragma unroll
      for (int j = 0; j < 4; ++j) acc[dg][j] *= alpha[j];
    // PV: V^T fragments direct from global (L2-hit)
    #pragma unroll
    for (int kb2 = 0; kb2 < 2; ++kb2) {
      bf16x8 pf = ld8(&Ps[w][lrow * PLD + kb2 * 32 + lk]);
      bf16x8 vf[8];
      #pragma unroll
      for (int dg = 0; dg < 8; ++dg)
        vf[dg] = ld8(vt_base + (size_t)(dg * 16 + lrow) * 1024 + kv0 + kb2 * 32 + lk);
      #pragma unroll
      for (int dg = 0; dg < 8; ++dg)
        acc[dg] = __builtin_amdgcn_mfma_f32_16x16x32_bf16(pf, vf[dg], acc[dg], 0, 0, 0);
    }
  }
  // epilogue
  #pragma unroll
  for (int j = 0; j < 4; ++j) {
    float rl = 1.0f / lsum[j];
    int t = b * 1024 + q0 + w * 16 + (lg << 2) + j;
    short* op = ob + ((size_t)t * 32 + h) * 128;
    #pragma unroll
    for (int dg = 0; dg < 8; ++dg)
      op[dg * 16 + lrow] = f2bf(acc[dg][j] * rl);
  }
}

// ---------------- launcher ----------------
extern "C" void kernel_launch(void* const* d_in, const int* in_sizes, int n_in,
                              void* d_out, int out_size, void* d_ws, size_t ws_size,
                              hipStream_t stream) {
  (void)in_sizes; (void)n_in; (void)out_size; (void)ws_size;
  const float* x    = (const float*)d_in[0];
  const float* qw   = (const float*)d_in[1];
  const float* kvw  = (const float*)d_in[2];
  const float* ow   = (const float*)d_in[3];
  const float* qnw  = (const float*)d_in[4];
  const float* knw  = (const float*)d_in[5];
  const float* cosb = (const float*)d_in[6];
  const float* sinb = (const float*)d_in[7];
  const float* kvbf = (const float*)d_in[8];
  const int*   idx  = (const int*)d_in[9];

  float* outp = (float*)d_out;
  float* bufp = outp + (size_t)2048 * 4096;   // 16384*2048 f32 = 134 MB

  // workspace (75.5 MB total)
  char* ws = (char*)d_ws;
  float* xqkv = (float*)ws;                                   // [2048][6144] f32, 50.3 MB
  short* qb   = (short*)(ws + (size_t)2048 * 6144 * 4);       // 16.8 MB
  short* kbp  = (short*)((char*)qb + (size_t)2048 * 4096 * 2); // 4.2 MB
  short* vbp  = (short*)((char*)kbp + (size_t)2048 * 1024 * 2);// 4.2 MB
  short* attnb = (short*)xqkv;                                // reuse after nr_k (16.8 MB)
  short* owt   = (short*)((char*)xqkv + (size_t)2048 * 4096 * 2); // reuse, 33.5 MB
  short* vbt   = owt;   // vbt (4.2 MB) lives in owt region DURING attn;
                        // tr_k(ow) overwrites it only after attn completes

  // scratch inside the (not-yet-written) kv_buffer output region:
  short* wqkvt = (short*)bufp;                                // [6144][4096] bf16, 50.3 MB
  short* xb    = (short*)((char*)bufp + (size_t)6144 * 4096 * 2); // [2048][4096] bf16, 16.8 MB

  // 1) pre-convert x to bf16; transpose fused [qw|kvw] -> bf16 [6144][4096]
  cvt_k<<<dim3(4096), dim3(256), 0, stream>>>(x, xb);
  tr_k<<<dim3(64 * 64), dim3(256), 0, stream>>>(qw, wqkvt, 4096, 4096);
  tr_k<<<dim3(64 * 32), dim3(256), 0, stream>>>(kvw, wqkvt + (size_t)4096 * 4096, 4096, 2048);
  // 2) fused QKV projection: [2048,4096] @ [4096,6144] -> [2048][6144]
  gemm_k<<<dim3(16 * 48), dim3(256), 0, stream>>>(xb, wqkvt, xqkv, 6144, 4096);
  // 3) kv buffer base copy: rows 2048.. only (rows 0..2047 fully rewritten by
  //    the scatter since cur_select_index covers them); kills wqkvt/xb scratch
  hipMemcpyAsync(bufp + (size_t)2048 * 2048, kvbf + (size_t)2048 * 2048,
                 (size_t)(16384 - 2048) * 2048 * 4, hipMemcpyDeviceToDevice, stream);
  nr_k<<<dim3(98304 / 4), dim3(256), 0, stream>>>(xqkv, qnw, knw, cosb, sinb, idx,
                                                  qb, kbp, vbp, bufp);
  // 4) V transpose for direct-global PV reads, then attention (no K/V staging)
  vtr_k<<<dim3(512), dim3(256), 0, stream>>>(vbp, vbt);
  attn_k<<<dim3(2 * 32 * 16), dim3(256), 0, stream>>>(qb, kbp, vbt, attnb);
  // 5) O-weight transpose (overwrites vbt region — attn done), then O-proj
  tr_k<<<dim3(64 * 64), dim3(256), 0, stream>>>(ow, owt, 4096, 4096);
  gemm_k<<<dim3(16 * 32), dim3(256), 0, stream>>>(attnb, owt, outp, 4096, 4096);
}

// Round 7
// 480.239 us; speedup vs baseline: 1.1802x; 1.1802x over previous
//
#include <hip/hip_runtime.h>

// ---------------- common types/helpers ----------------
typedef float fx4 __attribute__((ext_vector_type(4)));
typedef short s16x4 __attribute__((ext_vector_type(4)));
typedef short s16x8 __attribute__((ext_vector_type(8)));
typedef __bf16 bf16x8 __attribute__((ext_vector_type(8)));

__device__ __forceinline__ short f2bf(float f) {
  unsigned u = __builtin_bit_cast(unsigned, f);
  u += 0x7fffu + ((u >> 16) & 1u);   // RNE
  return (short)(u >> 16);
}

__device__ __forceinline__ bf16x8 ld8(const short* p) {
  s16x8 v = *(const s16x8*)p;
  return __builtin_bit_cast(bf16x8, v);
}

// async global->LDS, 16B per lane; LDS dest is wave-uniform base + lane*16
__device__ __forceinline__ void gld16(const void* g, void* l) {
  __builtin_amdgcn_global_load_lds(
      (const __attribute__((address_space(1))) unsigned*)g,
      (__attribute__((address_space(3))) unsigned*)l, 16, 0, 0);
}

// ---------------- f32 -> bf16 convert (x pre-conversion) ----------------
__global__ __launch_bounds__(256) void cvt_k(const float* __restrict__ in,
                                             short* __restrict__ out) {
  int i = (blockIdx.x * 256 + threadIdx.x) * 8;
  fx4 a = *(const fx4*)(in + i);
  fx4 b = *(const fx4*)(in + i + 4);
  s16x8 w;
  w[0] = f2bf(a[0]); w[1] = f2bf(a[1]); w[2] = f2bf(a[2]); w[3] = f2bf(a[3]);
  w[4] = f2bf(b[0]); w[5] = f2bf(b[1]); w[6] = f2bf(b[2]); w[7] = f2bf(b[3]);
  *(s16x8*)(out + i) = w;
}

// ---------------- transpose+convert: out[n][k] = bf16(in[k][n]) ----------------
// in: f32 [K,N] row-major; out: bf16 [N,K]; 64x64 tiles, 256 threads
__global__ __launch_bounds__(256) void tr_k(const float* __restrict__ in,
    short* __restrict__ out, int K, int N) {
  __shared__ short T[64][72];
  const int ktiles = K >> 6;
  const int tk0 = (blockIdx.x % ktiles) << 6;
  const int tn0 = (blockIdx.x / ktiles) << 6;
  const int tid = threadIdx.x;
  #pragma unroll
  for (int i = 0; i < 4; ++i) {
    int idx = i * 256 + tid;
    int k = idx >> 4, n4 = (idx & 15) << 2;
    fx4 v = *(const fx4*)(in + (size_t)(tk0 + k) * N + tn0 + n4);
    #pragma unroll
    for (int j = 0; j < 4; ++j) T[n4 + j][k] = f2bf(v[j]);
  }
  __syncthreads();
  #pragma unroll
  for (int i = 0; i < 2; ++i) {
    int idx = i * 256 + tid;
    int n = idx >> 3, k8 = (idx & 7) << 3;
    *(s16x8*)(out + (size_t)(tn0 + n) * K + tk0 + k8) = *(const s16x8*)&T[n][k8];
  }
}

// ---------------- V transpose: vbt[b][kvh][d][t] = vbp[t(b)][kvh][d] -------
// vbp: bf16 [2048][8][128]; vbt: bf16 [2][8][128][1024]; 64x64 tiles
__global__ __launch_bounds__(256) void vtr_k(const short* __restrict__ vbp,
                                             short* __restrict__ vbt) {
  __shared__ short T[64][72];   // T[d][t]
  const int tile = blockIdx.x & 31;
  const int tt = tile & 15, dt = tile >> 4;
  const int bk = blockIdx.x >> 5;
  const int b = bk >> 3, kvh = bk & 7;
  const int t0 = tt << 6, d0 = dt << 6;
  const int tid = threadIdx.x;
  #pragma unroll
  for (int i = 0; i < 2; ++i) {
    int idx = i * 256 + tid;
    int r = idx >> 3, c8 = (idx & 7) << 3;   // r = t-row, c8 = d-col
    s16x8 v = *(const s16x8*)(vbp + (size_t)(b * 1024 + t0 + r) * 1024 + kvh * 128 + d0 + c8);
    #pragma unroll
    for (int j = 0; j < 8; ++j) T[c8 + j][r] = v[j];
  }
  __syncthreads();
  #pragma unroll
  for (int i = 0; i < 2; ++i) {
    int idx = i * 256 + tid;
    int r = idx >> 3, c8 = (idx & 7) << 3;   // r = d-row, c8 = t-col
    *(s16x8*)(vbt + ((size_t)(b * 8 + kvh) * 128 + d0 + r) * 1024 + t0 + c8) =
        *(const s16x8*)&T[r][c8];
  }
}

// ---------------- GEMM: C[M,N] = A[M,K] @ Bt[N,K]^T  (all bf16 in, f32 out) ----
// 128x128 tile, BK=64, 4 waves (2x2), 4x4 16x16x32 frags/wave, 32 MFMA/step.
// T3 2-phase double-buffered pipeline; one __syncthreads per K-step.
__global__ __launch_bounds__(256) void gemm_k(const short* __restrict__ A,
    const short* __restrict__ Bt, float* __restrict__ Cp, int N, int K) {
  __shared__ short As[2][128 * 64];
  __shared__ short Bs[2][128 * 64];
  const int tiles_n = N >> 7;
  const int tm = blockIdx.x / tiles_n, tn = blockIdx.x % tiles_n;
  const int tid = threadIdx.x;
  const int lane = tid & 63, wv = tid >> 6;
  const int wr = (wv >> 1) << 6, wc = (wv & 1) << 6;
  const int r0 = tm << 7, c0 = tn << 7;
  const int lrow = lane & 15, lg = lane >> 4;
  const int srow = tid >> 3, sch = tid & 7;   // staging: 8 chunks per row
  fx4 acc[4][4] = {};

  auto stage = [&](int buf, int k0) {
    #pragma unroll
    for (int i = 0; i < 4; ++i) {
      int row = (i << 5) + srow;
      int gk = ((sch ^ (row & 7)) << 3);
      gld16(A + (size_t)(r0 + row) * K + k0 + gk, &As[buf][(i * 256 + wv * 64) * 8]);
    }
    #pragma unroll
    for (int i = 0; i < 4; ++i) {
      int row = (i << 5) + srow;
      int gk = ((sch ^ (row & 7)) << 3);
      gld16(Bt + (size_t)(c0 + row) * K + k0 + gk, &Bs[buf][(i * 256 + wv * 64) * 8]);
    }
  };

  const int nt = K >> 6;
  stage(0, 0);
  __syncthreads();          // drain prologue loads
  int cur = 0;
  for (int t = 0; t < nt; ++t) {
    if (t + 1 < nt) stage(cur ^ 1, (t + 1) << 6);   // loads fly during compute
    bf16x8 af[4][2], bfr[4][2];
    #pragma unroll
    for (int m = 0; m < 4; ++m) {
      int row = wr + m * 16 + lrow;
      #pragma unroll
      for (int h = 0; h < 2; ++h)
        af[m][h] = ld8(&As[cur][row * 64 + ((((h << 2) + lg) ^ (row & 7)) << 3)]);
    }
    #pragma unroll
    for (int n = 0; n < 4; ++n) {
      int row = wc + n * 16 + lrow;
      #pragma unroll
      for (int h = 0; h < 2; ++h)
        bfr[n][h] = ld8(&Bs[cur][row * 64 + ((((h << 2) + lg) ^ (row & 7)) << 3)]);
    }
    __builtin_amdgcn_s_setprio(1);
    #pragma unroll
    for (int m = 0; m < 4; ++m)
      #pragma unroll
      for (int n = 0; n < 4; ++n) {
        acc[m][n] = __builtin_amdgcn_mfma_f32_16x16x32_bf16(af[m][0], bfr[n][0], acc[m][n], 0, 0, 0);
        acc[m][n] = __builtin_amdgcn_mfma_f32_16x16x32_bf16(af[m][1], bfr[n][1], acc[m][n], 0, 0, 0);
      }
    __builtin_amdgcn_s_setprio(0);
    __syncthreads();        // drains vmcnt(0)+lgkmcnt(0): next tile resident, swap safe
    cur ^= 1;
  }
  // ---- epilogue: C layout col=lane&15, row=(lane>>4)*4+j ----
  const int g4 = lg << 2;
  #pragma unroll
  for (int m = 0; m < 4; ++m)
    #pragma unroll
    for (int n = 0; n < 4; ++n)
      #pragma unroll
      for (int j = 0; j < 4; ++j) {
        int row = r0 + wr + m * 16 + g4 + j;
        int col = c0 + wc + n * 16 + lrow;
        Cp[(size_t)row * N + col] = acc[m][n][j];
      }
}

// ---------------- RMSNorm + RoPE + KV scatter ----------------
// one wave per (token, head) row; lane l holds d=l and d=l+64 (rotate-half pairs)
// xqkv: f32 [2048][6144] — q at +0, k at +4096, v at +5120 (per token row)
__global__ __launch_bounds__(256) void nr_k(const float* __restrict__ xqkv,
    const float* __restrict__ qnw, const float* __restrict__ knw,
    const float* __restrict__ cosb, const float* __restrict__ sinb,
    const int* __restrict__ idx,
    short* __restrict__ qb, short* __restrict__ kbp, short* __restrict__ vbp,
    float* __restrict__ bufo) {
  int rid = blockIdx.x * 4 + (threadIdx.x >> 6);
  int l = threadIdx.x & 63;
  int type, t, h;
  if (rid < 65536)      { type = 0; t = rid >> 5; h = rid & 31; }
  else if (rid < 81920) { type = 1; int r = rid - 65536; t = r >> 3; h = r & 7; }
  else                  { type = 2; int r = rid - 81920; t = r >> 3; h = r & 7; }
  int s = t & 1023;
  const float* src = xqkv + (size_t)t * 6144 +
                     ((type == 0) ? h * 128 : (type == 1) ? 4096 + h * 128
                                                          : 5120 + h * 128);
  float e0 = src[l], e1 = src[l + 64];
  float out0, out1;
  if (type < 2) {
    float ss = e0 * e0 + e1 * e1;
    #pragma unroll
    for (int off = 1; off < 64; off <<= 1) ss += __shfl_xor(ss, off);
    float r = rsqrtf(ss * (1.0f / 128.0f) + 1e-6f);
    const float* nw = (type == 0) ? qnw : knw;
    float n0 = e0 * r * nw[l], n1 = e1 * r * nw[l + 64];
    float c0 = cosb[s * 128 + l], c1 = cosb[s * 128 + 64 + l];
    float s0 = sinb[s * 128 + l], s1 = sinb[s * 128 + 64 + l];
    out0 = n0 * c0 - n1 * s0;
    out1 = n1 * c1 + n0 * s1;
  } else { out0 = e0; out1 = e1; }
  if (type == 0) {
    short* d = qb + (size_t)t * 4096 + h * 128;
    d[l] = f2bf(out0); d[l + 64] = f2bf(out1);
  } else {
    int br = idx[t];
    float* bd = bufo + (size_t)br * 2048 + (type == 1 ? 0 : 1024) + h * 128;
    bd[l] = out0; bd[l + 64] = out1;
    short* d = (type == 1) ? kbp + (size_t)t * 1024 + h * 128
                           : vbp + (size_t)t * 1024 + h * 128;
    d[l] = f2bf(out0); d[l + 64] = f2bf(out1);
  }
}

// ---------------- causal GQA flash attention ----------------
// block = (b, h, 64-q-row tile), 4 waves of 16 q rows each, KV tiles of 64.
// K [64][128] and V^T [128][64] tiles staged via global_load_lds (zero VALU),
// LINEAR LDS dest; 16B chunks XOR'd with (row&7) on the global source and on
// ds_read (both-sides involution -> 2-way/free bank access). V comes from the
// pre-transposed vbt. Heavy tiles (large qt) dispatched first.
#define PLD 72

__global__ __launch_bounds__(256) void attn_k(const short* __restrict__ qb,
    const short* __restrict__ kbp, const short* __restrict__ vbt,
    short* __restrict__ ob) {
  __shared__ short Ks[64 * 128];
  __shared__ short Vs[128 * 64];
  __shared__ short Ps[4][16 * PLD];
  const int bid = blockIdx.x;
  const int qt = 15 - (bid & 15), h = (bid >> 4) & 31, b = bid >> 9;
  const int kvh = h >> 2;
  const int tid = threadIdx.x, lane = tid & 63, w = tid >> 6;
  const int lrow = lane & 15, lg = lane >> 4, lk = lg << 3;
  const int q0 = qt << 6;
  const float SC2 = 0.088388347648318447f * 1.4426950408889634f; // scale*log2(e)

  bf16x8 qf[4];
  {
    const short* qp = qb + ((size_t)(b * 1024 + q0 + w * 16 + lrow) * 32 + h) * 128 + lk;
    #pragma unroll
    for (int kb4 = 0; kb4 < 4; ++kb4) qf[kb4] = ld8(qp + kb4 * 32);
  }
  // K rows: kbp[(b*1024+t)*1024 + kvh*128 + d]; V^T rows: vbt[((b*8+kvh)*128+d)*1024 + t]
  const short* kb_base = kbp + (size_t)(b * 1024) * 1024 + kvh * 128;
  const short* vt_base = vbt + (size_t)(b * 8 + kvh) * 128 * 1024;
  const int krow = tid >> 2, kch = tid & 3;   // K staging: 4 chunks per iter-row
  const int vrow = tid >> 1, vch = tid & 1;   // V staging

  float m[4], lsum[4];
  fx4 acc[8] = {};
  #pragma unroll
  for (int j = 0; j < 4; ++j) { m[j] = -3.0e38f; lsum[j] = 0.f; }

  for (int kt = 0; kt <= qt; ++kt) {
    const int kv0 = kt << 6;
    // ---- stage K (64x128) + V^T (128x64) via global_load_lds ----
    #pragma unroll
    for (int i = 0; i < 4; ++i) {
      // chunk c = i*256+tid; K: row=c>>4 (0..63), ch=c&15
      int row = (i << 4) + (tid >> 4), ch = tid & 15;
      int gch = ch ^ (row & 7);
      gld16(kb_base + (size_t)(kv0 + row) * 1024 + (gch << 3),
            &Ks[(i * 256 + (tid >> 6) * 64) * 8]);
    }
    #pragma unroll
    for (int i = 0; i < 4; ++i) {
      // chunk c = i*256+tid; V: row=c>>3 (0..127), ch=c&7
      int row = (i << 5) + (tid >> 3), ch = tid & 7;
      int gch = ch ^ (row & 7);
      gld16(vt_base + (size_t)row * 1024 + kv0 + (gch << 3),
            &Vs[(i * 256 + (tid >> 6) * 64) * 8]);
    }
    __syncthreads();
    // ---- S = Q K^T (16x64 per wave) ----
    fx4 sf[4];
    #pragma unroll
    for (int nc = 0; nc < 4; ++nc) {
      fx4 z = {0.f, 0.f, 0.f, 0.f};
      sf[nc] = z;
      int row = nc * 16 + lrow;
      #pragma unroll
      for (int kb4 = 0; kb4 < 4; ++kb4) {
        bf16x8 kf = ld8(&Ks[row * 128 + ((((kb4 << 2) + lg) ^ (row & 7)) << 3)]);
        sf[nc] = __builtin_amdgcn_mfma_f32_16x16x32_bf16(qf[kb4], kf, sf[nc], 0, 0, 0);
      }
    }
    // causal mask on the diagonal tile
    if (kt == qt) {
      #pragma unroll
      for (int nc = 0; nc < 4; ++nc)
        #pragma unroll
        for (int j = 0; j < 4; ++j) {
          int qr = q0 + w * 16 + (lg << 2) + j;
          int kc = kv0 + nc * 16 + lrow;
          if (kc > qr) sf[nc][j] = -3.0e38f;
        }
    }
    // ---- online softmax ----
    float pm[4];
    #pragma unroll
    for (int j = 0; j < 4; ++j) pm[j] = -3.0e38f;
    #pragma unroll
    for (int nc = 0; nc < 4; ++nc)
      #pragma unroll
      for (int j = 0; j < 4; ++j) pm[j] = fmaxf(pm[j], sf[nc][j]);
    #pragma unroll
    for (int j = 0; j < 4; ++j) {
      pm[j] = fmaxf(pm[j], __shfl_xor(pm[j], 1));
      pm[j] = fmaxf(pm[j], __shfl_xor(pm[j], 2));
      pm[j] = fmaxf(pm[j], __shfl_xor(pm[j], 4));
      pm[j] = fmaxf(pm[j], __shfl_xor(pm[j], 8));
    }
    float alpha[4], rs[4];
    #pragma unroll
    for (int j = 0; j < 4; ++j) {
      float mn = fmaxf(m[j], pm[j]);
      alpha[j] = exp2f((m[j] - mn) * SC2);
      m[j] = mn;
      rs[j] = 0.f;
    }
    #pragma unroll
    for (int nc = 0; nc < 4; ++nc)
      #pragma unroll
      for (int j = 0; j < 4; ++j) {
        float p = exp2f((sf[nc][j] - m[j]) * SC2);
        rs[j] += p;
        Ps[w][((lg << 2) + j) * PLD + nc * 16 + lrow] = f2bf(p);
      }
    #pragma unroll
    for (int j = 0; j < 4; ++j) {
      rs[j] += __shfl_xor(rs[j], 1);
      rs[j] += __shfl_xor(rs[j], 2);
      rs[j] += __shfl_xor(rs[j], 4);
      rs[j] += __shfl_xor(rs[j], 8);
      lsum[j] = lsum[j] * alpha[j] + rs[j];
    }
    #pragma unroll
    for (int dg = 0; dg < 8; ++dg)
      #pragma unroll
      for (int j = 0; j < 4; ++j) acc[dg][j] *= alpha[j];
    // ---- PV ----
    #pragma unroll
    for (int kb2 = 0; kb2 < 2; ++kb2) {
      bf16x8 pf = ld8(&Ps[w][lrow * PLD + kb2 * 32 + lk]);
      #pragma unroll
      for (int dg = 0; dg < 8; ++dg) {
        int d = dg * 16 + lrow;
        bf16x8 vf = ld8(&Vs[d * 64 + ((((kb2 << 2) + lg) ^ (d & 7)) << 3)]);
        acc[dg] = __builtin_amdgcn_mfma_f32_16x16x32_bf16(pf, vf, acc[dg], 0, 0, 0);
      }
    }
    __syncthreads();   // all reads done before next tile's staging overwrites
  }
  // epilogue
  #pragma unroll
  for (int j = 0; j < 4; ++j) {
    float rl = 1.0f / lsum[j];
    int t = b * 1024 + q0 + w * 16 + (lg << 2) + j;
    short* op = ob + ((size_t)t * 32 + h) * 128;
    #pragma unroll
    for (int dg = 0; dg < 8; ++dg)
      op[dg * 16 + lrow] = f2bf(acc[dg][j] * rl);
  }
}

// ---------------- launcher ----------------
extern "C" void kernel_launch(void* const* d_in, const int* in_sizes, int n_in,
                              void* d_out, int out_size, void* d_ws, size_t ws_size,
                              hipStream_t stream) {
  (void)in_sizes; (void)n_in; (void)out_size; (void)ws_size;
  const float* x    = (const float*)d_in[0];
  const float* qw   = (const float*)d_in[1];
  const float* kvw  = (const float*)d_in[2];
  const float* ow   = (const float*)d_in[3];
  const float* qnw  = (const float*)d_in[4];
  const float* knw  = (const float*)d_in[5];
  const float* cosb = (const float*)d_in[6];
  const float* sinb = (const float*)d_in[7];
  const float* kvbf = (const float*)d_in[8];
  const int*   idx  = (const int*)d_in[9];

  float* outp = (float*)d_out;
  float* bufp = outp + (size_t)2048 * 4096;   // 16384*2048 f32 = 134 MB

  // workspace (75.5 MB total)
  char* ws = (char*)d_ws;
  float* xqkv = (float*)ws;                                   // [2048][6144] f32, 50.3 MB
  short* qb   = (short*)(ws + (size_t)2048 * 6144 * 4);       // 16.8 MB
  short* kbp  = (short*)((char*)qb + (size_t)2048 * 4096 * 2); // 4.2 MB
  short* vbp  = (short*)((char*)kbp + (size_t)2048 * 1024 * 2);// 4.2 MB
  short* attnb = (short*)xqkv;                                // reuse after nr_k (16.8 MB)
  short* owt   = (short*)((char*)xqkv + (size_t)2048 * 4096 * 2); // reuse, 33.5 MB
  short* vbt   = owt;   // vbt (4.2 MB) lives in owt region DURING attn;
                        // tr_k(ow) overwrites it only after attn completes

  // scratch inside the (not-yet-written) kv_buffer output region:
  short* wqkvt = (short*)bufp;                                // [6144][4096] bf16, 50.3 MB
  short* xb    = (short*)((char*)bufp + (size_t)6144 * 4096 * 2); // [2048][4096] bf16, 16.8 MB

  // 1) pre-convert x to bf16; transpose fused [qw|kvw] -> bf16 [6144][4096]
  cvt_k<<<dim3(4096), dim3(256), 0, stream>>>(x, xb);
  tr_k<<<dim3(64 * 64), dim3(256), 0, stream>>>(qw, wqkvt, 4096, 4096);
  tr_k<<<dim3(64 * 32), dim3(256), 0, stream>>>(kvw, wqkvt + (size_t)4096 * 4096, 4096, 2048);
  // 2) fused QKV projection: [2048,4096] @ [4096,6144] -> [2048][6144]
  gemm_k<<<dim3(16 * 48), dim3(256), 0, stream>>>(xb, wqkvt, xqkv, 6144, 4096);
  // 3) kv buffer base copy: rows 2048.. only (rows 0..2047 fully rewritten by
  //    the scatter since cur_select_index covers them); kills wqkvt/xb scratch
  hipMemcpyAsync(bufp + (size_t)2048 * 2048, kvbf + (size_t)2048 * 2048,
                 (size_t)(16384 - 2048) * 2048 * 4, hipMemcpyDeviceToDevice, stream);
  nr_k<<<dim3(98304 / 4), dim3(256), 0, stream>>>(xqkv, qnw, knw, cosb, sinb, idx,
                                                  qb, kbp, vbp, bufp);
  // 4) V transpose once, then attention (LDS-staged via global_load_lds)
  vtr_k<<<dim3(512), dim3(256), 0, stream>>>(vbp, vbt);
  attn_k<<<dim3(2 * 32 * 16), dim3(256), 0, stream>>>(qb, kbp, vbt, attnb);
  // 5) O-weight transpose (overwrites vbt region — attn done), then O-proj
  tr_k<<<dim3(64 * 64), dim3(256), 0, stream>>>(ow, owt, 4096, 4096);
  gemm_k<<<dim3(16 * 32), dim3(256), 0, stream>>>(attnb, owt, outp, 4096, 4096);
}

// Round 8
// 437.226 us; speedup vs baseline: 1.2963x; 1.0984x over previous
//
#include <hip/hip_runtime.h>

// ---------------- common types/helpers ----------------
typedef float fx4 __attribute__((ext_vector_type(4)));
typedef short s16x4 __attribute__((ext_vector_type(4)));
typedef short s16x8 __attribute__((ext_vector_type(8)));
typedef __bf16 bf16x8 __attribute__((ext_vector_type(8)));

__device__ __forceinline__ short f2bf(float f) {
  unsigned u = __builtin_bit_cast(unsigned, f);
  u += 0x7fffu + ((u >> 16) & 1u);   // RNE
  return (short)(u >> 16);
}

__device__ __forceinline__ bf16x8 ld8(const short* p) {
  s16x8 v = *(const s16x8*)p;
  return __builtin_bit_cast(bf16x8, v);
}

// async global->LDS, 16B per lane; LDS dest is wave-uniform base + lane*16
__device__ __forceinline__ void gld16(const void* g, void* l) {
  __builtin_amdgcn_global_load_lds(
      (const __attribute__((address_space(1))) unsigned*)g,
      (__attribute__((address_space(3))) unsigned*)l, 16, 0, 0);
}

// ---------------- f32 -> bf16 convert (x pre-conversion) ----------------
__global__ __launch_bounds__(256) void cvt_k(const float* __restrict__ in,
                                             short* __restrict__ out) {
  int i = (blockIdx.x * 256 + threadIdx.x) * 8;
  fx4 a = *(const fx4*)(in + i);
  fx4 b = *(const fx4*)(in + i + 4);
  s16x8 w;
  w[0] = f2bf(a[0]); w[1] = f2bf(a[1]); w[2] = f2bf(a[2]); w[3] = f2bf(a[3]);
  w[4] = f2bf(b[0]); w[5] = f2bf(b[1]); w[6] = f2bf(b[2]); w[7] = f2bf(b[3]);
  *(s16x8*)(out + i) = w;
}

// ---------------- transpose+convert: out[n][k] = bf16(in[k][n]) ----------------
// in: f32 [K,N] row-major; out: bf16 [N,K]; 64x64 tiles, 256 threads
__global__ __launch_bounds__(256) void tr_k(const float* __restrict__ in,
    short* __restrict__ out, int K, int N) {
  __shared__ short T[64][72];
  const int ktiles = K >> 6;
  const int tk0 = (blockIdx.x % ktiles) << 6;
  const int tn0 = (blockIdx.x / ktiles) << 6;
  const int tid = threadIdx.x;
  #pragma unroll
  for (int i = 0; i < 4; ++i) {
    int idx = i * 256 + tid;
    int k = idx >> 4, n4 = (idx & 15) << 2;
    fx4 v = *(const fx4*)(in + (size_t)(tk0 + k) * N + tn0 + n4);
    #pragma unroll
    for (int j = 0; j < 4; ++j) T[n4 + j][k] = f2bf(v[j]);
  }
  __syncthreads();
  #pragma unroll
  for (int i = 0; i < 2; ++i) {
    int idx = i * 256 + tid;
    int n = idx >> 3, k8 = (idx & 7) << 3;
    *(s16x8*)(out + (size_t)(tn0 + n) * K + tk0 + k8) = *(const s16x8*)&T[n][k8];
  }
}

// ---------------- GEMM: C[M,N] = A[M,K] @ Bt[N,K]^T  (all bf16 in, f32 out) ----
// 128x128 tile, BK=64, 4 waves (2x2), 4x4 16x16x32 frags/wave, 32 MFMA/step.
// T3 2-phase double-buffered pipeline; one __syncthreads per K-step.
__global__ __launch_bounds__(256) void gemm_k(const short* __restrict__ A,
    const short* __restrict__ Bt, float* __restrict__ Cp, int N, int K) {
  __shared__ short As[2][128 * 64];
  __shared__ short Bs[2][128 * 64];
  const int tiles_n = N >> 7;
  const int tm = blockIdx.x / tiles_n, tn = blockIdx.x % tiles_n;
  const int tid = threadIdx.x;
  const int lane = tid & 63, wv = tid >> 6;
  const int wr = (wv >> 1) << 6, wc = (wv & 1) << 6;
  const int r0 = tm << 7, c0 = tn << 7;
  const int lrow = lane & 15, lg = lane >> 4;
  const int srow = tid >> 3, sch = tid & 7;   // staging: 8 chunks per row
  fx4 acc[4][4] = {};

  auto stage = [&](int buf, int k0) {
    #pragma unroll
    for (int i = 0; i < 4; ++i) {
      int row = (i << 5) + srow;
      int gk = ((sch ^ (row & 7)) << 3);
      gld16(A + (size_t)(r0 + row) * K + k0 + gk, &As[buf][(i * 256 + wv * 64) * 8]);
    }
    #pragma unroll
    for (int i = 0; i < 4; ++i) {
      int row = (i << 5) + srow;
      int gk = ((sch ^ (row & 7)) << 3);
      gld16(Bt + (size_t)(c0 + row) * K + k0 + gk, &Bs[buf][(i * 256 + wv * 64) * 8]);
    }
  };

  const int nt = K >> 6;
  stage(0, 0);
  __syncthreads();          // drain prologue loads
  int cur = 0;
  for (int t = 0; t < nt; ++t) {
    if (t + 1 < nt) stage(cur ^ 1, (t + 1) << 6);   // loads fly during compute
    bf16x8 af[4][2], bfr[4][2];
    #pragma unroll
    for (int m = 0; m < 4; ++m) {
      int row = wr + m * 16 + lrow;
      #pragma unroll
      for (int h = 0; h < 2; ++h)
        af[m][h] = ld8(&As[cur][row * 64 + ((((h << 2) + lg) ^ (row & 7)) << 3)]);
    }
    #pragma unroll
    for (int n = 0; n < 4; ++n) {
      int row = wc + n * 16 + lrow;
      #pragma unroll
      for (int h = 0; h < 2; ++h)
        bfr[n][h] = ld8(&Bs[cur][row * 64 + ((((h << 2) + lg) ^ (row & 7)) << 3)]);
    }
    __builtin_amdgcn_s_setprio(1);
    #pragma unroll
    for (int m = 0; m < 4; ++m)
      #pragma unroll
      for (int n = 0; n < 4; ++n) {
        acc[m][n] = __builtin_amdgcn_mfma_f32_16x16x32_bf16(af[m][0], bfr[n][0], acc[m][n], 0, 0, 0);
        acc[m][n] = __builtin_amdgcn_mfma_f32_16x16x32_bf16(af[m][1], bfr[n][1], acc[m][n], 0, 0, 0);
      }
    __builtin_amdgcn_s_setprio(0);
    __syncthreads();        // drains vmcnt(0)+lgkmcnt(0): next tile resident, swap safe
    cur ^= 1;
  }
  // ---- epilogue: C layout col=lane&15, row=(lane>>4)*4+j ----
  const int g4 = lg << 2;
  #pragma unroll
  for (int m = 0; m < 4; ++m)
    #pragma unroll
    for (int n = 0; n < 4; ++n)
      #pragma unroll
      for (int j = 0; j < 4; ++j) {
        int row = r0 + wr + m * 16 + g4 + j;
        int col = c0 + wc + n * 16 + lrow;
        Cp[(size_t)row * N + col] = acc[m][n][j];
      }
}

// ---------------- RMSNorm + RoPE + KV scatter ----------------
// one wave per (token, head) row; lane l holds d=l and d=l+64 (rotate-half pairs)
// xqkv: f32 [2048][6144] — q at +0, k at +4096, v at +5120 (per token row)
__global__ __launch_bounds__(256) void nr_k(const float* __restrict__ xqkv,
    const float* __restrict__ qnw, const float* __restrict__ knw,
    const float* __restrict__ cosb, const float* __restrict__ sinb,
    const int* __restrict__ idx,
    short* __restrict__ qb, short* __restrict__ kbp, short* __restrict__ vbp,
    float* __restrict__ bufo) {
  int rid = blockIdx.x * 4 + (threadIdx.x >> 6);
  int l = threadIdx.x & 63;
  int type, t, h;
  if (rid < 65536)      { type = 0; t = rid >> 5; h = rid & 31; }
  else if (rid < 81920) { type = 1; int r = rid - 65536; t = r >> 3; h = r & 7; }
  else                  { type = 2; int r = rid - 81920; t = r >> 3; h = r & 7; }
  int s = t & 1023;
  const float* src = xqkv + (size_t)t * 6144 +
                     ((type == 0) ? h * 128 : (type == 1) ? 4096 + h * 128
                                                          : 5120 + h * 128);
  float e0 = src[l], e1 = src[l + 64];
  float out0, out1;
  if (type < 2) {
    float ss = e0 * e0 + e1 * e1;
    #pragma unroll
    for (int off = 1; off < 64; off <<= 1) ss += __shfl_xor(ss, off);
    float r = rsqrtf(ss * (1.0f / 128.0f) + 1e-6f);
    const float* nw = (type == 0) ? qnw : knw;
    float n0 = e0 * r * nw[l], n1 = e1 * r * nw[l + 64];
    float c0 = cosb[s * 128 + l], c1 = cosb[s * 128 + 64 + l];
    float s0 = sinb[s * 128 + l], s1 = sinb[s * 128 + 64 + l];
    out0 = n0 * c0 - n1 * s0;
    out1 = n1 * c1 + n0 * s1;
  } else { out0 = e0; out1 = e1; }
  if (type == 0) {
    short* d = qb + (size_t)t * 4096 + h * 128;
    d[l] = f2bf(out0); d[l + 64] = f2bf(out1);
  } else {
    int br = idx[t];
    float* bd = bufo + (size_t)br * 2048 + (type == 1 ? 0 : 1024) + h * 128;
    bd[l] = out0; bd[l + 64] = out1;
    short* d = (type == 1) ? kbp + (size_t)t * 1024 + h * 128
                           : vbp + (size_t)t * 1024 + h * 128;
    d[l] = f2bf(out0); d[l + 64] = f2bf(out1);
  }
}

// ---------------- causal GQA flash attention ----------------
// block = (b, h, 64-q-row tile), 4 waves of 16 q rows each, KV tiles of 64.
// Round-4 verified structure (reg-staged K + in-LDS V transpose) + T14
// async-STAGE split: tile kt+1's global loads are ISSUED before tile kt's
// compute (latency hides under QK/softmax/PV) and WRITTEN to LDS after the
// read-barrier. Heavy tiles (large qt) dispatched first.
#define KLD 136
#define VLD 72
#define PLD 72

__global__ __launch_bounds__(256) void attn_k(const short* __restrict__ qb,
    const short* __restrict__ kbp, const short* __restrict__ vbp,
    short* __restrict__ ob) {
  __shared__ short Ks[64 * KLD];
  __shared__ short Vs[128 * VLD];
  __shared__ short Ps[4][16 * PLD];
  const int bid = blockIdx.x;
  const int qt = 15 - (bid & 15), h = (bid >> 4) & 31, b = bid >> 9;
  const int kvh = h >> 2;
  const int tid = threadIdx.x, lane = tid & 63, w = tid >> 6;
  const int lrow = lane & 15, lg = lane >> 4, lk = lg << 3;
  const int q0 = qt << 6;
  const float SC2 = 0.088388347648318447f * 1.4426950408889634f; // scale*log2(e)

  bf16x8 qf[4];
  {
    const short* qp = qb + ((size_t)(b * 1024 + q0 + w * 16 + lrow) * 32 + h) * 128 + lk;
    #pragma unroll
    for (int kb4 = 0; kb4 < 4; ++kb4) qf[kb4] = ld8(qp + kb4 * 32);
  }

  // staging indices: idx = it*256+tid -> r = idx>>4 (0..63), d8 = (idx&15)<<3
  const int sr = tid >> 4, sd8 = (tid & 15) << 3;
  s16x8 kreg[4], vreg[4];
  auto ldkv = [&](int kv0) {
    #pragma unroll
    for (int it = 0; it < 4; ++it) {
      int r = (it << 4) + sr;
      size_t base = ((size_t)(b * 1024 + kv0 + r) * 8 + kvh) * 128 + sd8;
      kreg[it] = *(const s16x8*)(kbp + base);
      vreg[it] = *(const s16x8*)(vbp + base);
    }
  };
  auto wrkv = [&]() {
    #pragma unroll
    for (int it = 0; it < 4; ++it) {
      int r = (it << 4) + sr;
      *(s16x8*)&Ks[r * KLD + sd8] = kreg[it];
      int swz = ((sd8 >> 3) & 7) << 3;
      #pragma unroll
      for (int j = 0; j < 8; ++j)
        Vs[(sd8 + j) * VLD + (r ^ swz)] = vreg[it][j];
    }
  };

  float m[4], lsum[4];
  fx4 acc[8] = {};
  #pragma unroll
  for (int j = 0; j < 4; ++j) { m[j] = -3.0e38f; lsum[j] = 0.f; }

  ldkv(0);
  wrkv();
  __syncthreads();

  for (int kt = 0; kt <= qt; ++kt) {
    const int kv0 = kt << 6;
    if (kt < qt) ldkv((kt + 1) << 6);   // T14: issue next tile's loads early
    // ---- S = Q K^T (16x64 per wave) ----
    fx4 sf[4];
    #pragma unroll
    for (int nc = 0; nc < 4; ++nc) {
      fx4 z = {0.f, 0.f, 0.f, 0.f};
      sf[nc] = z;
      #pragma unroll
      for (int kb4 = 0; kb4 < 4; ++kb4) {
        bf16x8 kf = ld8(&Ks[(nc * 16 + lrow) * KLD + kb4 * 32 + lk]);
        sf[nc] = __builtin_amdgcn_mfma_f32_16x16x32_bf16(qf[kb4], kf, sf[nc], 0, 0, 0);
      }
    }
    // causal mask on the diagonal tile
    if (kt == qt) {
      #pragma unroll
      for (int nc = 0; nc < 4; ++nc)
        #pragma unroll
        for (int j = 0; j < 4; ++j) {
          int qr = q0 + w * 16 + (lg << 2) + j;
          int kc = kv0 + nc * 16 + lrow;
          if (kc > qr) sf[nc][j] = -3.0e38f;
        }
    }
    // ---- online softmax ----
    float pm[4];
    #pragma unroll
    for (int j = 0; j < 4; ++j) pm[j] = -3.0e38f;
    #pragma unroll
    for (int nc = 0; nc < 4; ++nc)
      #pragma unroll
      for (int j = 0; j < 4; ++j) pm[j] = fmaxf(pm[j], sf[nc][j]);
    #pragma unroll
    for (int j = 0; j < 4; ++j) {
      pm[j] = fmaxf(pm[j], __shfl_xor(pm[j], 1));
      pm[j] = fmaxf(pm[j], __shfl_xor(pm[j], 2));
      pm[j] = fmaxf(pm[j], __shfl_xor(pm[j], 4));
      pm[j] = fmaxf(pm[j], __shfl_xor(pm[j], 8));
    }
    float alpha[4], rs[4];
    #pragma unroll
    for (int j = 0; j < 4; ++j) {
      float mn = fmaxf(m[j], pm[j]);
      alpha[j] = exp2f((m[j] - mn) * SC2);
      m[j] = mn;
      rs[j] = 0.f;
    }
    #pragma unroll
    for (int nc = 0; nc < 4; ++nc)
      #pragma unroll
      for (int j = 0; j < 4; ++j) {
        float p = exp2f((sf[nc][j] - m[j]) * SC2);
        rs[j] += p;
        Ps[w][((lg << 2) + j) * PLD + nc * 16 + lrow] = f2bf(p);
      }
    #pragma unroll
    for (int j = 0; j < 4; ++j) {
      rs[j] += __shfl_xor(rs[j], 1);
      rs[j] += __shfl_xor(rs[j], 2);
      rs[j] += __shfl_xor(rs[j], 4);
      rs[j] += __shfl_xor(rs[j], 8);
      lsum[j] = lsum[j] * alpha[j] + rs[j];
    }
    #pragma unroll
    for (int dg = 0; dg < 8; ++dg)
      #pragma unroll
      for (int j = 0; j < 4; ++j) acc[dg][j] *= alpha[j];
    // ---- PV ----
    #pragma unroll
    for (int kb2 = 0; kb2 < 2; ++kb2) {
      bf16x8 pf = ld8(&Ps[w][lrow * PLD + kb2 * 32 + lk]);
      #pragma unroll
      for (int dg = 0; dg < 8; ++dg) {
        int d = dg * 16 + lrow;
        int kvs = (kb2 * 32 + lk) ^ (((d >> 3) & 7) << 3);
        bf16x8 vf = ld8(&Vs[d * VLD + kvs]);
        acc[dg] = __builtin_amdgcn_mfma_f32_16x16x32_bf16(pf, vf, acc[dg], 0, 0, 0);
      }
    }
    __syncthreads();              // all waves done READING Ks/Vs
    if (kt < qt) {
      wrkv();                     // write prefetched tile (regs already loaded)
      __syncthreads();            // writes visible before next compute
    }
  }
  // epilogue
  #pragma unroll
  for (int j = 0; j < 4; ++j) {
    float rl = 1.0f / lsum[j];
    int t = b * 1024 + q0 + w * 16 + (lg << 2) + j;
    short* op = ob + ((size_t)t * 32 + h) * 128;
    #pragma unroll
    for (int dg = 0; dg < 8; ++dg)
      op[dg * 16 + lrow] = f2bf(acc[dg][j] * rl);
  }
}

// ---------------- launcher ----------------
extern "C" void kernel_launch(void* const* d_in, const int* in_sizes, int n_in,
                              void* d_out, int out_size, void* d_ws, size_t ws_size,
                              hipStream_t stream) {
  (void)in_sizes; (void)n_in; (void)out_size; (void)ws_size;
  const float* x    = (const float*)d_in[0];
  const float* qw   = (const float*)d_in[1];
  const float* kvw  = (const float*)d_in[2];
  const float* ow   = (const float*)d_in[3];
  const float* qnw  = (const float*)d_in[4];
  const float* knw  = (const float*)d_in[5];
  const float* cosb = (const float*)d_in[6];
  const float* sinb = (const float*)d_in[7];
  const float* kvbf = (const float*)d_in[8];
  const int*   idx  = (const int*)d_in[9];

  float* outp = (float*)d_out;
  float* bufp = outp + (size_t)2048 * 4096;   // 16384*2048 f32 = 134 MB

  // workspace (75.5 MB total)
  char* ws = (char*)d_ws;
  float* xqkv = (float*)ws;                                   // [2048][6144] f32, 50.3 MB
  short* qb   = (short*)(ws + (size_t)2048 * 6144 * 4);       // 16.8 MB
  short* kbp  = (short*)((char*)qb + (size_t)2048 * 4096 * 2); // 4.2 MB
  short* vbp  = (short*)((char*)kbp + (size_t)2048 * 1024 * 2);// 4.2 MB
  short* attnb = (short*)xqkv;                                // reuse after nr_k (16.8 MB)
  short* owt   = (short*)((char*)xqkv + (size_t)2048 * 4096 * 2); // reuse, 33.5 MB

  // scratch inside the (not-yet-written) kv_buffer output region:
  short* wqkvt = (short*)bufp;                                // [6144][4096] bf16, 50.3 MB
  short* xb    = (short*)((char*)bufp + (size_t)6144 * 4096 * 2); // [2048][4096] bf16, 16.8 MB

  // 1) pre-convert x to bf16; transpose fused [qw|kvw] -> bf16 [6144][4096]
  cvt_k<<<dim3(4096), dim3(256), 0, stream>>>(x, xb);
  tr_k<<<dim3(64 * 64), dim3(256), 0, stream>>>(qw, wqkvt, 4096, 4096);
  tr_k<<<dim3(64 * 32), dim3(256), 0, stream>>>(kvw, wqkvt + (size_t)4096 * 4096, 4096, 2048);
  // 2) fused QKV projection: [2048,4096] @ [4096,6144] -> [2048][6144]
  gemm_k<<<dim3(16 * 48), dim3(256), 0, stream>>>(xb, wqkvt, xqkv, 6144, 4096);
  // 3) kv buffer base copy: rows 2048.. only (rows 0..2047 fully rewritten by
  //    the scatter since cur_select_index covers them); kills wqkvt/xb scratch
  hipMemcpyAsync(bufp + (size_t)2048 * 2048, kvbf + (size_t)2048 * 2048,
                 (size_t)(16384 - 2048) * 2048 * 4, hipMemcpyDeviceToDevice, stream);
  nr_k<<<dim3(98304 / 4), dim3(256), 0, stream>>>(xqkv, qnw, knw, cosb, sinb, idx,
                                                  qb, kbp, vbp, bufp);
  // 4) O-weight transpose into dead xqkv region; attention (reg-staged + T14)
  tr_k<<<dim3(64 * 64), dim3(256), 0, stream>>>(ow, owt, 4096, 4096);
  attn_k<<<dim3(2 * 32 * 16), dim3(256), 0, stream>>>(qb, kbp, vbp, attnb);
  // 5) O-proj
  gemm_k<<<dim3(16 * 32), dim3(256), 0, stream>>>(attnb, owt, outp, 4096, 4096);
}

// Round 9
// 429.180 us; speedup vs baseline: 1.3206x; 1.0187x over previous
//
#include <hip/hip_runtime.h>

// ---------------- common types/helpers ----------------
typedef float fx4 __attribute__((ext_vector_type(4)));
typedef short s16x4 __attribute__((ext_vector_type(4)));
typedef short s16x8 __attribute__((ext_vector_type(8)));
typedef __bf16 bf16x8 __attribute__((ext_vector_type(8)));

__device__ __forceinline__ short f2bf(float f) {
  unsigned u = __builtin_bit_cast(unsigned, f);
  u += 0x7fffu + ((u >> 16) & 1u);   // RNE
  return (short)(u >> 16);
}

__device__ __forceinline__ bf16x8 ld8(const short* p) {
  s16x8 v = *(const s16x8*)p;
  return __builtin_bit_cast(bf16x8, v);
}

// async global->LDS, 16B per lane; LDS dest is wave-uniform base + lane*16
__device__ __forceinline__ void gld16(const void* g, void* l) {
  __builtin_amdgcn_global_load_lds(
      (const __attribute__((address_space(1))) unsigned*)g,
      (__attribute__((address_space(3))) unsigned*)l, 16, 0, 0);
}

// ---------------- f32 -> bf16 convert (x pre-conversion) ----------------
__global__ __launch_bounds__(256) void cvt_k(const float* __restrict__ in,
                                             short* __restrict__ out) {
  int i = (blockIdx.x * 256 + threadIdx.x) * 8;
  fx4 a = *(const fx4*)(in + i);
  fx4 b = *(const fx4*)(in + i + 4);
  s16x8 w;
  w[0] = f2bf(a[0]); w[1] = f2bf(a[1]); w[2] = f2bf(a[2]); w[3] = f2bf(a[3]);
  w[4] = f2bf(b[0]); w[5] = f2bf(b[1]); w[6] = f2bf(b[2]); w[7] = f2bf(b[3]);
  *(s16x8*)(out + i) = w;
}

// ---------------- transpose+convert: out[n][k] = bf16(in[k][n]) ----------------
// in: f32 [K,N] row-major; out: bf16 [N,K]; 64x64 tiles, 256 threads
__global__ __launch_bounds__(256) void tr_k(const float* __restrict__ in,
    short* __restrict__ out, int K, int N) {
  __shared__ short T[64][72];
  const int ktiles = K >> 6;
  const int tk0 = (blockIdx.x % ktiles) << 6;
  const int tn0 = (blockIdx.x / ktiles) << 6;
  const int tid = threadIdx.x;
  #pragma unroll
  for (int i = 0; i < 4; ++i) {
    int idx = i * 256 + tid;
    int k = idx >> 4, n4 = (idx & 15) << 2;
    fx4 v = *(const fx4*)(in + (size_t)(tk0 + k) * N + tn0 + n4);
    #pragma unroll
    for (int j = 0; j < 4; ++j) T[n4 + j][k] = f2bf(v[j]);
  }
  __syncthreads();
  #pragma unroll
  for (int i = 0; i < 2; ++i) {
    int idx = i * 256 + tid;
    int n = idx >> 3, k8 = (idx & 7) << 3;
    *(s16x8*)(out + (size_t)(tn0 + n) * K + tk0 + k8) = *(const s16x8*)&T[n][k8];
  }
}

// ---------------- V transpose: vbt[b][kvh][d][t] = vbp[t(b)][kvh][d] -------
// vbp: bf16 [2048][8][128]; vbt: bf16 [2][8][128][1024]; 64x64 tiles
__global__ __launch_bounds__(256) void vtr_k(const short* __restrict__ vbp,
                                             short* __restrict__ vbt) {
  __shared__ short T[64][72];   // T[d][t]
  const int tile = blockIdx.x & 31;
  const int tt = tile & 15, dt = tile >> 4;
  const int bk = blockIdx.x >> 5;
  const int b = bk >> 3, kvh = bk & 7;
  const int t0 = tt << 6, d0 = dt << 6;
  const int tid = threadIdx.x;
  #pragma unroll
  for (int i = 0; i < 2; ++i) {
    int idx = i * 256 + tid;
    int r = idx >> 3, c8 = (idx & 7) << 3;   // r = t-row, c8 = d-col
    s16x8 v = *(const s16x8*)(vbp + (size_t)(b * 1024 + t0 + r) * 1024 + kvh * 128 + d0 + c8);
    #pragma unroll
    for (int j = 0; j < 8; ++j) T[c8 + j][r] = v[j];
  }
  __syncthreads();
  #pragma unroll
  for (int i = 0; i < 2; ++i) {
    int idx = i * 256 + tid;
    int r = idx >> 3, c8 = (idx & 7) << 3;   // r = d-row, c8 = t-col
    *(s16x8*)(vbt + ((size_t)(b * 8 + kvh) * 128 + d0 + r) * 1024 + t0 + c8) =
        *(const s16x8*)&T[r][c8];
  }
}

// ---------------- GEMM: C[M,N] = A[M,K] @ Bt[N,K]^T  (all bf16 in, f32 out) ----
// 128x128 tile, BK=64, 4 waves (2x2), 4x4 16x16x32 frags/wave, 32 MFMA/step.
// T3 2-phase double-buffered pipeline; one __syncthreads per K-step.
__global__ __launch_bounds__(256) void gemm_k(const short* __restrict__ A,
    const short* __restrict__ Bt, float* __restrict__ Cp, int N, int K) {
  __shared__ short As[2][128 * 64];
  __shared__ short Bs[2][128 * 64];
  const int tiles_n = N >> 7;
  const int tm = blockIdx.x / tiles_n, tn = blockIdx.x % tiles_n;
  const int tid = threadIdx.x;
  const int lane = tid & 63, wv = tid >> 6;
  const int wr = (wv >> 1) << 6, wc = (wv & 1) << 6;
  const int r0 = tm << 7, c0 = tn << 7;
  const int lrow = lane & 15, lg = lane >> 4;
  const int srow = tid >> 3, sch = tid & 7;   // staging: 8 chunks per row
  fx4 acc[4][4] = {};

  auto stage = [&](int buf, int k0) {
    #pragma unroll
    for (int i = 0; i < 4; ++i) {
      int row = (i << 5) + srow;
      int gk = ((sch ^ (row & 7)) << 3);
      gld16(A + (size_t)(r0 + row) * K + k0 + gk, &As[buf][(i * 256 + wv * 64) * 8]);
    }
    #pragma unroll
    for (int i = 0; i < 4; ++i) {
      int row = (i << 5) + srow;
      int gk = ((sch ^ (row & 7)) << 3);
      gld16(Bt + (size_t)(c0 + row) * K + k0 + gk, &Bs[buf][(i * 256 + wv * 64) * 8]);
    }
  };

  const int nt = K >> 6;
  stage(0, 0);
  __syncthreads();          // drain prologue loads
  int cur = 0;
  for (int t = 0; t < nt; ++t) {
    if (t + 1 < nt) stage(cur ^ 1, (t + 1) << 6);   // loads fly during compute
    bf16x8 af[4][2], bfr[4][2];
    #pragma unroll
    for (int m = 0; m < 4; ++m) {
      int row = wr + m * 16 + lrow;
      #pragma unroll
      for (int h = 0; h < 2; ++h)
        af[m][h] = ld8(&As[cur][row * 64 + ((((h << 2) + lg) ^ (row & 7)) << 3)]);
    }
    #pragma unroll
    for (int n = 0; n < 4; ++n) {
      int row = wc + n * 16 + lrow;
      #pragma unroll
      for (int h = 0; h < 2; ++h)
        bfr[n][h] = ld8(&Bs[cur][row * 64 + ((((h << 2) + lg) ^ (row & 7)) << 3)]);
    }
    __builtin_amdgcn_s_setprio(1);
    #pragma unroll
    for (int m = 0; m < 4; ++m)
      #pragma unroll
      for (int n = 0; n < 4; ++n) {
        acc[m][n] = __builtin_amdgcn_mfma_f32_16x16x32_bf16(af[m][0], bfr[n][0], acc[m][n], 0, 0, 0);
        acc[m][n] = __builtin_amdgcn_mfma_f32_16x16x32_bf16(af[m][1], bfr[n][1], acc[m][n], 0, 0, 0);
      }
    __builtin_amdgcn_s_setprio(0);
    __syncthreads();        // drains vmcnt(0)+lgkmcnt(0): next tile resident, swap safe
    cur ^= 1;
  }
  // ---- epilogue: C layout col=lane&15, row=(lane>>4)*4+j ----
  const int g4 = lg << 2;
  #pragma unroll
  for (int m = 0; m < 4; ++m)
    #pragma unroll
    for (int n = 0; n < 4; ++n)
      #pragma unroll
      for (int j = 0; j < 4; ++j) {
        int row = r0 + wr + m * 16 + g4 + j;
        int col = c0 + wc + n * 16 + lrow;
        Cp[(size_t)row * N + col] = acc[m][n][j];
      }
}

// ---------------- RMSNorm + RoPE + KV scatter ----------------
// one wave per (token, head) row; lane l holds d=l and d=l+64 (rotate-half pairs)
// xqkv: f32 [2048][6144] — q at +0, k at +4096, v at +5120 (per token row)
__global__ __launch_bounds__(256) void nr_k(const float* __restrict__ xqkv,
    const float* __restrict__ qnw, const float* __restrict__ knw,
    const float* __restrict__ cosb, const float* __restrict__ sinb,
    const int* __restrict__ idx,
    short* __restrict__ qb, short* __restrict__ kbp, short* __restrict__ vbp,
    float* __restrict__ bufo) {
  int rid = blockIdx.x * 4 + (threadIdx.x >> 6);
  int l = threadIdx.x & 63;
  int type, t, h;
  if (rid < 65536)      { type = 0; t = rid >> 5; h = rid & 31; }
  else if (rid < 81920) { type = 1; int r = rid - 65536; t = r >> 3; h = r & 7; }
  else                  { type = 2; int r = rid - 81920; t = r >> 3; h = r & 7; }
  int s = t & 1023;
  const float* src = xqkv + (size_t)t * 6144 +
                     ((type == 0) ? h * 128 : (type == 1) ? 4096 + h * 128
                                                          : 5120 + h * 128);
  float e0 = src[l], e1 = src[l + 64];
  float out0, out1;
  if (type < 2) {
    float ss = e0 * e0 + e1 * e1;
    #pragma unroll
    for (int off = 1; off < 64; off <<= 1) ss += __shfl_xor(ss, off);
    float r = rsqrtf(ss * (1.0f / 128.0f) + 1e-6f);
    const float* nw = (type == 0) ? qnw : knw;
    float n0 = e0 * r * nw[l], n1 = e1 * r * nw[l + 64];
    float c0 = cosb[s * 128 + l], c1 = cosb[s * 128 + 64 + l];
    float s0 = sinb[s * 128 + l], s1 = sinb[s * 128 + 64 + l];
    out0 = n0 * c0 - n1 * s0;
    out1 = n1 * c1 + n0 * s1;
  } else { out0 = e0; out1 = e1; }
  if (type == 0) {
    short* d = qb + (size_t)t * 4096 + h * 128;
    d[l] = f2bf(out0); d[l + 64] = f2bf(out1);
  } else {
    int br = idx[t];
    float* bd = bufo + (size_t)br * 2048 + (type == 1 ? 0 : 1024) + h * 128;
    bd[l] = out0; bd[l + 64] = out1;
    short* d = (type == 1) ? kbp + (size_t)t * 1024 + h * 128
                           : vbp + (size_t)t * 1024 + h * 128;
    d[l] = f2bf(out0); d[l + 64] = f2bf(out1);
  }
}

// ---------------- causal GQA flash attention ----------------
// block = (b, h, 64-q-row tile), 4 waves of 16 q rows each, KV tiles of 64.
// Reg-staged K (row-major, KLD pad) + reg-staged V^T from the globally
// pre-transposed vbt: 4 coalesced b128 reads + 4 XOR-swizzled b128 ds_writes
// (replaces 32 scalar conflicted writes/thread). T14 early issue for both.
// Sync structure identical to the verified round-4 form.
#define KLD 136
#define PLD 72

__global__ __launch_bounds__(256) void attn_k(const short* __restrict__ qb,
    const short* __restrict__ kbp, const short* __restrict__ vbt,
    short* __restrict__ ob) {
  __shared__ short Ks[64 * KLD];
  __shared__ short Vs[128 * 64];
  __shared__ short Ps[4][16 * PLD];
  const int bid = blockIdx.x;
  const int qt = 15 - (bid & 15), h = (bid >> 4) & 31, b = bid >> 9;
  const int kvh = h >> 2;
  const int tid = threadIdx.x, lane = tid & 63, w = tid >> 6;
  const int lrow = lane & 15, lg = lane >> 4, lk = lg << 3;
  const int q0 = qt << 6;
  const float SC2 = 0.088388347648318447f * 1.4426950408889634f; // scale*log2(e)

  bf16x8 qf[4];
  {
    const short* qp = qb + ((size_t)(b * 1024 + q0 + w * 16 + lrow) * 32 + h) * 128 + lk;
    #pragma unroll
    for (int kb4 = 0; kb4 < 4; ++kb4) qf[kb4] = ld8(qp + kb4 * 32);
  }

  const short* vt_base = vbt + (size_t)(b * 8 + kvh) * 128 * 1024;

  // K staging: idx = it*256+tid -> r = idx>>4 (0..63), d8 = (idx&15)<<3
  const int sr = tid >> 4, sd8 = (tid & 15) << 3;
  // V^T staging: idx = it*256+tid -> d = it*32 + (tid>>3), ch = tid&7
  const int vdr = tid >> 3, vch = tid & 7;
  s16x8 kreg[4], vreg[4];
  auto ldkv = [&](int kv0) {
    #pragma unroll
    for (int it = 0; it < 4; ++it) {
      int r = (it << 4) + sr;
      kreg[it] = *(const s16x8*)(kbp + ((size_t)(b * 1024 + kv0 + r) * 8 + kvh) * 128 + sd8);
      int d = (it << 5) + vdr;
      vreg[it] = *(const s16x8*)(vt_base + (size_t)d * 1024 + kv0 + (vch << 3));
    }
  };
  auto wrkv = [&]() {
    #pragma unroll
    for (int it = 0; it < 4; ++it) {
      int r = (it << 4) + sr;
      *(s16x8*)&Ks[r * KLD + sd8] = kreg[it];
      int d = (it << 5) + vdr;
      *(s16x8*)&Vs[d * 64 + ((vch ^ (d & 7)) << 3)] = vreg[it];
    }
  };

  float m[4], lsum[4];
  fx4 acc[8] = {};
  #pragma unroll
  for (int j = 0; j < 4; ++j) { m[j] = -3.0e38f; lsum[j] = 0.f; }

  ldkv(0);
  wrkv();
  __syncthreads();

  for (int kt = 0; kt <= qt; ++kt) {
    const int kv0 = kt << 6;
    if (kt < qt) ldkv((kt + 1) << 6);   // T14: issue next tile's loads early
    // ---- S = Q K^T (16x64 per wave) ----
    fx4 sf[4];
    #pragma unroll
    for (int nc = 0; nc < 4; ++nc) {
      fx4 z = {0.f, 0.f, 0.f, 0.f};
      sf[nc] = z;
      #pragma unroll
      for (int kb4 = 0; kb4 < 4; ++kb4) {
        bf16x8 kf = ld8(&Ks[(nc * 16 + lrow) * KLD + kb4 * 32 + lk]);
        sf[nc] = __builtin_amdgcn_mfma_f32_16x16x32_bf16(qf[kb4], kf, sf[nc], 0, 0, 0);
      }
    }
    // causal mask on the diagonal tile
    if (kt == qt) {
      #pragma unroll
      for (int nc = 0; nc < 4; ++nc)
        #pragma unroll
        for (int j = 0; j < 4; ++j) {
          int qr = q0 + w * 16 + (lg << 2) + j;
          int kc = kv0 + nc * 16 + lrow;
          if (kc > qr) sf[nc][j] = -3.0e38f;
        }
    }
    // ---- online softmax ----
    float pm[4];
    #pragma unroll
    for (int j = 0; j < 4; ++j) pm[j] = -3.0e38f;
    #pragma unroll
    for (int nc = 0; nc < 4; ++nc)
      #pragma unroll
      for (int j = 0; j < 4; ++j) pm[j] = fmaxf(pm[j], sf[nc][j]);
    #pragma unroll
    for (int j = 0; j < 4; ++j) {
      pm[j] = fmaxf(pm[j], __shfl_xor(pm[j], 1));
      pm[j] = fmaxf(pm[j], __shfl_xor(pm[j], 2));
      pm[j] = fmaxf(pm[j], __shfl_xor(pm[j], 4));
      pm[j] = fmaxf(pm[j], __shfl_xor(pm[j], 8));
    }
    float alpha[4], rs[4];
    #pragma unroll
    for (int j = 0; j < 4; ++j) {
      float mn = fmaxf(m[j], pm[j]);
      alpha[j] = exp2f((m[j] - mn) * SC2);
      m[j] = mn;
      rs[j] = 0.f;
    }
    #pragma unroll
    for (int nc = 0; nc < 4; ++nc)
      #pragma unroll
      for (int j = 0; j < 4; ++j) {
        float p = exp2f((sf[nc][j] - m[j]) * SC2);
        rs[j] += p;
        Ps[w][((lg << 2) + j) * PLD + nc * 16 + lrow] = f2bf(p);
      }
    #pragma unroll
    for (int j = 0; j < 4; ++j) {
      rs[j] += __shfl_xor(rs[j], 1);
      rs[j] += __shfl_xor(rs[j], 2);
      rs[j] += __shfl_xor(rs[j], 4);
      rs[j] += __shfl_xor(rs[j], 8);
      lsum[j] = lsum[j] * alpha[j] + rs[j];
    }
    #pragma unroll
    for (int dg = 0; dg < 8; ++dg)
      #pragma unroll
      for (int j = 0; j < 4; ++j) acc[dg][j] *= alpha[j];
    // ---- PV (V^T in Vs[d][t-chunks], XOR-involution read: 2-way/free) ----
    #pragma unroll
    for (int kb2 = 0; kb2 < 2; ++kb2) {
      bf16x8 pf = ld8(&Ps[w][lrow * PLD + kb2 * 32 + lk]);
      #pragma unroll
      for (int dg = 0; dg < 8; ++dg) {
        int d = dg * 16 + lrow;
        int tch = (kb2 << 2) + lg;
        bf16x8 vf = ld8(&Vs[d * 64 + ((tch ^ (d & 7)) << 3)]);
        acc[dg] = __builtin_amdgcn_mfma_f32_16x16x32_bf16(pf, vf, acc[dg], 0, 0, 0);
      }
    }
    __syncthreads();              // all waves done READING Ks/Vs
    if (kt < qt) {
      wrkv();                     // write prefetched tile (regs already loaded)
      __syncthreads();            // writes visible before next compute
    }
  }
  // epilogue
  #pragma unroll
  for (int j = 0; j < 4; ++j) {
    float rl = 1.0f / lsum[j];
    int t = b * 1024 + q0 + w * 16 + (lg << 2) + j;
    short* op = ob + ((size_t)t * 32 + h) * 128;
    #pragma unroll
    for (int dg = 0; dg < 8; ++dg)
      op[dg * 16 + lrow] = f2bf(acc[dg][j] * rl);
  }
}

// ---------------- launcher ----------------
extern "C" void kernel_launch(void* const* d_in, const int* in_sizes, int n_in,
                              void* d_out, int out_size, void* d_ws, size_t ws_size,
                              hipStream_t stream) {
  (void)in_sizes; (void)n_in; (void)out_size; (void)ws_size;
  const float* x    = (const float*)d_in[0];
  const float* qw   = (const float*)d_in[1];
  const float* kvw  = (const float*)d_in[2];
  const float* ow   = (const float*)d_in[3];
  const float* qnw  = (const float*)d_in[4];
  const float* knw  = (const float*)d_in[5];
  const float* cosb = (const float*)d_in[6];
  const float* sinb = (const float*)d_in[7];
  const float* kvbf = (const float*)d_in[8];
  const int*   idx  = (const int*)d_in[9];

  float* outp = (float*)d_out;
  float* bufp = outp + (size_t)2048 * 4096;   // 16384*2048 f32 = 134 MB

  // workspace (75.5 MB total)
  char* ws = (char*)d_ws;
  float* xqkv = (float*)ws;                                   // [2048][6144] f32, 50.3 MB
  short* qb   = (short*)(ws + (size_t)2048 * 6144 * 4);       // 16.8 MB
  short* kbp  = (short*)((char*)qb + (size_t)2048 * 4096 * 2); // 4.2 MB
  short* vbp  = (short*)((char*)kbp + (size_t)2048 * 1024 * 2);// 4.2 MB
  short* attnb = (short*)xqkv;                                // reuse after nr_k (16.8 MB)
  short* owt   = (short*)((char*)xqkv + (size_t)2048 * 4096 * 2); // reuse, 33.5 MB
  short* vbt   = owt;   // vbt (4.2 MB) lives in owt region DURING attn;
                        // tr_k(ow) overwrites it only after attn completes

  // scratch inside the (not-yet-written) kv_buffer output region:
  short* wqkvt = (short*)bufp;                                // [6144][4096] bf16, 50.3 MB
  short* xb    = (short*)((char*)bufp + (size_t)6144 * 4096 * 2); // [2048][4096] bf16, 16.8 MB

  // 1) pre-convert x to bf16; transpose fused [qw|kvw] -> bf16 [6144][4096]
  cvt_k<<<dim3(4096), dim3(256), 0, stream>>>(x, xb);
  tr_k<<<dim3(64 * 64), dim3(256), 0, stream>>>(qw, wqkvt, 4096, 4096);
  tr_k<<<dim3(64 * 32), dim3(256), 0, stream>>>(kvw, wqkvt + (size_t)4096 * 4096, 4096, 2048);
  // 2) fused QKV projection: [2048,4096] @ [4096,6144] -> [2048][6144]
  gemm_k<<<dim3(16 * 48), dim3(256), 0, stream>>>(xb, wqkvt, xqkv, 6144, 4096);
  // 3) kv buffer base copy: rows 2048.. only (rows 0..2047 fully rewritten by
  //    the scatter since cur_select_index covers them); kills wqkvt/xb scratch
  hipMemcpyAsync(bufp + (size_t)2048 * 2048, kvbf + (size_t)2048 * 2048,
                 (size_t)(16384 - 2048) * 2048 * 4, hipMemcpyDeviceToDevice, stream);
  nr_k<<<dim3(98304 / 4), dim3(256), 0, stream>>>(xqkv, qnw, knw, cosb, sinb, idx,
                                                  qb, kbp, vbp, bufp);
  // 4) V transpose once (into owt region), then attention
  vtr_k<<<dim3(512), dim3(256), 0, stream>>>(vbp, vbt);
  attn_k<<<dim3(2 * 32 * 16), dim3(256), 0, stream>>>(qb, kbp, vbt, attnb);
  // 5) O-weight transpose (overwrites vbt — attn done), then O-proj
  tr_k<<<dim3(64 * 64), dim3(256), 0, stream>>>(ow, owt, 4096, 4096);
  gemm_k<<<dim3(16 * 32), dim3(256), 0, stream>>>(attnb, owt, outp, 4096, 4096);
}